// Round 1
// baseline (3688.545 us; speedup 1.0000x reference)
//
#include <hip/hip_runtime.h>

#define NPART 1000000
#define NGRID 128
#define NNODES (NGRID * NGRID)

// Output flat offsets (in floats), return order: x, v, C, F, material, Jp
#define OUT_X   0
#define OUT_V   2000000
#define OUT_C   4000000
#define OUT_F   8000000
#define OUT_MAT 12000000
#define OUT_JP  13000000

__device__ __forceinline__ void quad_weights(float fx, float w[3]) {
    w[0] = 0.5f * (1.5f - fx) * (1.5f - fx);
    w[1] = 0.75f - (fx - 1.0f) * (fx - 1.0f);
    w[2] = 0.5f * (fx - 0.5f) * (fx - 0.5f);
}

__global__ __launch_bounds__(256) void p2g_kernel(
    const float2* __restrict__ x, const float2* __restrict__ v,
    const float4* __restrict__ C, const float4* __restrict__ F,
    const int* __restrict__ material, const float* __restrict__ Jp,
    float* __restrict__ out,
    float* __restrict__ gv, float* __restrict__ gaff, float* __restrict__ gm)
{
    int n = blockIdx.x * blockDim.x + threadIdx.x;
    if (n >= NPART) return;

    const float DT = 1e-4f;
    const float INV_DX = 128.0f;
    const float P_MASS = 1.52587890625e-05f;              // (dx/2)^2 * rho, exact
    const float MU_0 = (float)(1000.0 / (2.0 * 1.2));     // E/(2(1+nu))
    const float LAMBDA_0 = (float)(200.0 / 0.72);         // E*nu/((1+nu)(1-2nu))
    const float SCALE = -1e-4f;                           // -DT*P_VOL*4*INV_DX^2 == -DT exactly

    float2 xx = x[n];
    float2 vv = v[n];
    float4 Cm = C[n];
    float4 Fin = F[n];
    int mat = material[n];
    float jp = Jp[n];

    float xg0 = xx.x * INV_DX, xg1 = xx.y * INV_DX;
    int b0 = (int)floorf(xg0 - 0.5f), b1 = (int)floorf(xg1 - 0.5f);
    float fx0 = xg0 - (float)b0, fx1 = xg1 - (float)b1;
    float wx[3], wy[3];
    quad_weights(fx0, wx);
    quad_weights(fx1, wy);

    // F_new = F + DT * C @ F
    float F00 = Fin.x + DT * (Cm.x * Fin.x + Cm.y * Fin.z);
    float F01 = Fin.y + DT * (Cm.x * Fin.y + Cm.y * Fin.w);
    float F10 = Fin.z + DT * (Cm.z * Fin.x + Cm.w * Fin.z);
    float F11 = Fin.w + DT * (Cm.z * Fin.y + Cm.w * Fin.w);

    float h = (mat == 1) ? 0.3f : expf(10.0f * (1.0f - jp));
    float mu = (mat == 0) ? 0.0f : MU_0 * h;
    float lam = LAMBDA_0 * h;

    // --- closed-form 2x2 SVD: F_new = U diag(s1,s2) V^T, U=R(u), V=R(vang)
    float Es = 0.5f * (F00 + F11), Fs = 0.5f * (F00 - F11);
    float Gs = 0.5f * (F01 + F10), Hs = 0.5f * (F10 - F01);
    float Qs = sqrtf(Es * Es + Hs * Hs);
    float Rs = sqrtf(Fs * Fs + Gs * Gs);
    float s1 = Qs + Rs, s2 = Qs - Rs;
    float a_sum = atan2f(Gs, Fs);   // u + v
    float a_dif = atan2f(Hs, Es);   // u - v
    float ua = 0.5f * (a_sum + a_dif);
    float va = 0.5f * (a_sum - a_dif);
    float su, cu, sv, sv_c;
    sincosf(ua, &su, &cu);
    sincosf(va, &sv, &sv_c);
    float cv = sv_c;

    float c1 = fminf(fmaxf(s1, 1.0f - 2.5e-2f), 1.0f + 4.5e-3f);
    float c2 = fminf(fmaxf(s2, 1.0f - 2.5e-2f), 1.0f + 4.5e-3f);
    float jp_new = jp;
    float sg1 = s1, sg2 = s2;
    if (mat == 2) {
        jp_new = jp * (s1 / c1) * (s2 / c2);
        sg1 = c1;
        sg2 = c2;
    }
    float J = sg1 * sg2;

    // R = U V^T (polar rotation)
    float R00 = cu * cv + su * sv;
    float R01 = cu * sv - su * cv;
    float R10 = su * cv - cu * sv;
    float R11 = su * sv + cu * cv;

    // projected F
    float o00, o01, o10, o11;
    if (mat == 0) {
        float sq = sqrtf(J);
        o00 = sq; o01 = 0.0f; o10 = 0.0f; o11 = sq;
    } else if (mat == 2) {
        o00 = sg1 * cu * cv + sg2 * su * sv;
        o01 = sg1 * cu * sv - sg2 * su * cv;
        o10 = sg1 * su * cv - sg2 * cu * sv;
        o11 = sg1 * su * sv + sg2 * cu * cv;
    } else {
        o00 = F00; o01 = F01; o10 = F10; o11 = F11;
    }

    // stress = 2*mu*(F-R)F^T + lam*J*(J-1)*I, scaled by -DT
    float A00 = o00 - R00, A01 = o01 - R01, A10 = o10 - R10, A11 = o11 - R11;
    float S00 = A00 * o00 + A01 * o01;
    float S01 = A00 * o10 + A01 * o11;
    float S10 = A10 * o00 + A11 * o01;
    float S11 = A10 * o10 + A11 * o11;
    float ljj = lam * J * (J - 1.0f);
    float aff00 = SCALE * (2.0f * mu * S00 + ljj) + P_MASS * Cm.x;
    float aff01 = SCALE * (2.0f * mu * S01)       + P_MASS * Cm.y;
    float aff10 = SCALE * (2.0f * mu * S10)       + P_MASS * Cm.z;
    float aff11 = SCALE * (2.0f * mu * S11 + ljj) + P_MASS * Cm.w;

    float mom0 = P_MASS * vv.x - (aff00 * xx.x + aff01 * xx.y);
    float mom1 = P_MASS * vv.y - (aff10 * xx.x + aff11 * xx.y);

    // per-particle outputs
    ((float4*)(out + OUT_F))[n] = make_float4(o00, o01, o10, o11);
    out[OUT_MAT + n] = (float)mat;
    out[OUT_JP + n] = jp_new;

    // scatter: 9 nodes x 7 floats
    #pragma unroll
    for (int i = 0; i < 3; ++i) {
        #pragma unroll
        for (int j = 0; j < 3; ++j) {
            float wt = wx[i] * wy[j];
            int idx = (b0 + i) * NGRID + (b1 + j);
            unsafeAtomicAdd(&gv[2 * idx + 0], wt * mom0);
            unsafeAtomicAdd(&gv[2 * idx + 1], wt * mom1);
            unsafeAtomicAdd(&gaff[4 * idx + 0], wt * aff00);
            unsafeAtomicAdd(&gaff[4 * idx + 1], wt * aff01);
            unsafeAtomicAdd(&gaff[4 * idx + 2], wt * aff10);
            unsafeAtomicAdd(&gaff[4 * idx + 3], wt * aff11);
            unsafeAtomicAdd(&gm[idx], wt * P_MASS);
        }
    }
}

__global__ __launch_bounds__(256) void grid_kernel(
    float* __restrict__ gv, const float* __restrict__ gaff,
    const float* __restrict__ gm)
{
    int idx = blockIdx.x * blockDim.x + threadIdx.x;
    if (idx >= NNODES) return;
    const float DX = 1.0f / 128.0f;
    const float DT = 1e-4f;
    int i = idx >> 7, j = idx & 127;
    float m = gm[idx];
    float v0 = gv[2 * idx], v1 = gv[2 * idx + 1];
    float a00 = gaff[4 * idx], a01 = gaff[4 * idx + 1];
    float a10 = gaff[4 * idx + 2], a11 = gaff[4 * idx + 3];
    float gx0 = (float)i * DX, gx1 = (float)j * DX;
    v0 += a00 * gx0 + a01 * gx1;
    v1 += a10 * gx0 + a11 * gx1;
    if (m > 0.0f) {
        v0 /= m;
        v1 /= m;
        v1 += -DT * 50.0f;
    }
    if (i < 3) v0 = fmaxf(v0, 0.0f);
    if (i >= NGRID - 2) v0 = fminf(v0, 0.0f);
    if (j < 3) v1 = fmaxf(v1, 0.0f);
    if (j >= NGRID - 2) v1 = fminf(v1, 0.0f);
    gv[2 * idx] = v0;
    gv[2 * idx + 1] = v1;
}

__global__ __launch_bounds__(256) void g2p_kernel(
    const float2* __restrict__ x, const float* __restrict__ gv,
    float* __restrict__ out)
{
    int n = blockIdx.x * blockDim.x + threadIdx.x;
    if (n >= NPART) return;
    const float DX = 1.0f / 128.0f;
    const float DT = 1e-4f;
    const float INV_DX = 128.0f;
    const float K4 = 65536.0f;  // 4*INV_DX^2

    float2 xx = x[n];
    float xg0 = xx.x * INV_DX, xg1 = xx.y * INV_DX;
    int b0 = (int)floorf(xg0 - 0.5f), b1 = (int)floorf(xg1 - 0.5f);
    float fx0 = xg0 - (float)b0, fx1 = xg1 - (float)b1;
    float wx[3], wy[3];
    quad_weights(fx0, wx);
    quad_weights(fx1, wy);

    float nv0 = 0.0f, nv1 = 0.0f;
    float nC00 = 0.0f, nC01 = 0.0f, nC10 = 0.0f, nC11 = 0.0f;
    #pragma unroll
    for (int i = 0; i < 3; ++i) {
        #pragma unroll
        for (int j = 0; j < 3; ++j) {
            float wt = wx[i] * wy[j];
            int idx = (b0 + i) * NGRID + (b1 + j);
            float g0 = gv[2 * idx], g1 = gv[2 * idx + 1];
            float node0 = (float)(b0 + i) * DX;
            float node1 = (float)(b1 + j) * DX;
            nv0 += wt * g0;
            nv1 += wt * g1;
            nC00 += wt * g0 * node0;
            nC01 += wt * g0 * node1;
            nC10 += wt * g1 * node0;
            nC11 += wt * g1 * node1;
        }
    }
    nC00 = (nC00 - nv0 * xx.x) * K4;
    nC01 = (nC01 - nv0 * xx.y) * K4;
    nC10 = (nC10 - nv1 * xx.x) * K4;
    nC11 = (nC11 - nv1 * xx.y) * K4;

    ((float2*)(out + OUT_X))[n] = make_float2(xx.x + DT * nv0, xx.y + DT * nv1);
    ((float2*)(out + OUT_V))[n] = make_float2(nv0, nv1);
    ((float4*)(out + OUT_C))[n] = make_float4(nC00, nC01, nC10, nC11);
}

extern "C" void kernel_launch(void* const* d_in, const int* in_sizes, int n_in,
                              void* d_out, int out_size, void* d_ws, size_t ws_size,
                              hipStream_t stream)
{
    const float2* x = (const float2*)d_in[0];
    const float2* v = (const float2*)d_in[1];
    const float4* C = (const float4*)d_in[2];
    const float4* F = (const float4*)d_in[3];
    const int* material = (const int*)d_in[4];
    const float* Jp = (const float*)d_in[5];
    float* out = (float*)d_out;

    float* gv = (float*)d_ws;            // 2 * NNODES floats
    float* gaff = gv + 2 * NNODES;       // 4 * NNODES floats
    float* gm = gaff + 4 * NNODES;       // NNODES floats

    hipMemsetAsync(d_ws, 0, (size_t)(7 * NNODES) * sizeof(float), stream);

    dim3 blk(256);
    dim3 grd((NPART + 255) / 256);
    p2g_kernel<<<grd, blk, 0, stream>>>(x, v, C, F, material, Jp, out, gv, gaff, gm);
    grid_kernel<<<NNODES / 256, blk, 0, stream>>>(gv, gaff, gm);
    g2p_kernel<<<grd, blk, 0, stream>>>(x, gv, out);
}

// Round 2
// 378.669 us; speedup vs baseline: 9.7408x; 9.7408x over previous
//
#include <hip/hip_runtime.h>

#define NPART 1000000
#define NGRID 128
#define NNODES (NGRID * NGRID)
#define NBLK 3907              // ceil(NPART/256)
#define NBINS 64               // 8x8 tiles of 16x16 nodes
#define SUBW 18                // 16 + 2 halo (high side)
#define SUBN (SUBW * SUBW)     // 324
#define P2G_SUB 8              // sub-blocks per tile
#define P2G_THREADS 512

// Output flat offsets (floats), return order: x, v, C, F, material, Jp
#define OUT_X   0
#define OUT_V   2000000
#define OUT_C   4000000
#define OUT_F   8000000
#define OUT_MAT 12000000
#define OUT_JP  13000000

__device__ __forceinline__ void quad_weights(float fx, float w[3]) {
    w[0] = 0.5f * (1.5f - fx) * (1.5f - fx);
    w[1] = 0.75f - (fx - 1.0f) * (fx - 1.0f);
    w[2] = 0.5f * (fx - 0.5f) * (fx - 0.5f);
}

struct PhysOut {
    float o00, o01, o10, o11;      // projected F (output)
    float aff00, aff01, aff10, aff11;
    float mom0, mom1;
    float jp_new;
};

__device__ __forceinline__ PhysOut particle_phys(
    float2 xx, float2 vv, float4 Cm, float4 Fin, int mat, float jp)
{
    const float DT = 1e-4f;
    const float P_MASS = 1.52587890625e-05f;
    const float MU_0 = (float)(1000.0 / (2.0 * 1.2));
    const float LAMBDA_0 = (float)(200.0 / 0.72);
    const float SCALE = -1e-4f;   // -DT*P_VOL*4*INV_DX^2 == -DT exactly

    float F00 = Fin.x + DT * (Cm.x * Fin.x + Cm.y * Fin.z);
    float F01 = Fin.y + DT * (Cm.x * Fin.y + Cm.y * Fin.w);
    float F10 = Fin.z + DT * (Cm.z * Fin.x + Cm.w * Fin.z);
    float F11 = Fin.w + DT * (Cm.z * Fin.y + Cm.w * Fin.w);

    float h = (mat == 1) ? 0.3f : expf(10.0f * (1.0f - jp));
    float mu = (mat == 0) ? 0.0f : MU_0 * h;
    float lam = LAMBDA_0 * h;

    // closed-form 2x2 SVD
    float Es = 0.5f * (F00 + F11), Fs = 0.5f * (F00 - F11);
    float Gs = 0.5f * (F01 + F10), Hs = 0.5f * (F10 - F01);
    float Qs = sqrtf(Es * Es + Hs * Hs);
    float Rs = sqrtf(Fs * Fs + Gs * Gs);
    float s1 = Qs + Rs, s2 = Qs - Rs;
    float a_sum = atan2f(Gs, Fs);
    float a_dif = atan2f(Hs, Es);
    float ua = 0.5f * (a_sum + a_dif);
    float va = 0.5f * (a_sum - a_dif);
    float su, cu, sv, cv;
    sincosf(ua, &su, &cu);
    sincosf(va, &sv, &cv);

    float c1 = fminf(fmaxf(s1, 1.0f - 2.5e-2f), 1.0f + 4.5e-3f);
    float c2 = fminf(fmaxf(s2, 1.0f - 2.5e-2f), 1.0f + 4.5e-3f);
    float jp_new = jp;
    float sg1 = s1, sg2 = s2;
    if (mat == 2) {
        jp_new = jp * (s1 / c1) * (s2 / c2);
        sg1 = c1;
        sg2 = c2;
    }
    float J = sg1 * sg2;

    float R00 = cu * cv + su * sv;
    float R01 = cu * sv - su * cv;
    float R10 = su * cv - cu * sv;
    float R11 = su * sv + cu * cv;

    float o00, o01, o10, o11;
    if (mat == 0) {
        float sq = sqrtf(J);
        o00 = sq; o01 = 0.0f; o10 = 0.0f; o11 = sq;
    } else if (mat == 2) {
        o00 = sg1 * cu * cv + sg2 * su * sv;
        o01 = sg1 * cu * sv - sg2 * su * cv;
        o10 = sg1 * su * cv - sg2 * cu * sv;
        o11 = sg1 * su * sv + sg2 * cu * cv;
    } else {
        o00 = F00; o01 = F01; o10 = F10; o11 = F11;
    }

    float A00 = o00 - R00, A01 = o01 - R01, A10 = o10 - R10, A11 = o11 - R11;
    float S00 = A00 * o00 + A01 * o01;
    float S01 = A00 * o10 + A01 * o11;
    float S10 = A10 * o00 + A11 * o01;
    float S11 = A10 * o10 + A11 * o11;
    float ljj = lam * J * (J - 1.0f);

    PhysOut po;
    po.o00 = o00; po.o01 = o01; po.o10 = o10; po.o11 = o11;
    po.aff00 = SCALE * (2.0f * mu * S00 + ljj) + P_MASS * Cm.x;
    po.aff01 = SCALE * (2.0f * mu * S01)       + P_MASS * Cm.y;
    po.aff10 = SCALE * (2.0f * mu * S10)       + P_MASS * Cm.z;
    po.aff11 = SCALE * (2.0f * mu * S11 + ljj) + P_MASS * Cm.w;
    po.mom0 = P_MASS * vv.x - (po.aff00 * xx.x + po.aff01 * xx.y);
    po.mom1 = P_MASS * vv.y - (po.aff10 * xx.x + po.aff11 * xx.y);
    po.jp_new = jp_new;
    return po;
}

__device__ __forceinline__ int tile_of(float2 xx) {
    int b0 = (int)floorf(xx.x * 128.0f - 0.5f);
    int b1 = (int)floorf(xx.y * 128.0f - 0.5f);
    return ((b0 >> 4) << 3) | (b1 >> 4);
}

// ---- Pass 1: per-block histogram over 64 tiles (all-LDS) ----
__global__ __launch_bounds__(256) void hist_kernel(
    const float2* __restrict__ x, int* __restrict__ blockHist)
{
    __shared__ int lh[NBINS];
    int tid = threadIdx.x, bid = blockIdx.x;
    if (tid < NBINS) lh[tid] = 0;
    __syncthreads();
    int n = bid * 256 + tid;
    if (n < NPART) atomicAdd(&lh[tile_of(x[n])], 1);
    __syncthreads();
    if (tid < NBINS) blockHist[tid * NBLK + bid] = lh[tid];
}

// ---- Pass 2: per-bin exclusive scan over blocks (64 blocks) ----
__global__ __launch_bounds__(256) void scan_kernel(
    int* __restrict__ blockHist, int* __restrict__ binCount)
{
    __shared__ int tmp[256];
    int b = blockIdx.x, tid = threadIdx.x;
    int* arr = blockHist + b * NBLK;
    int carry = 0;
    for (int base = 0; base < NBLK; base += 256) {
        int i = base + tid;
        int vL = (i < NBLK) ? arr[i] : 0;
        tmp[tid] = vL;
        __syncthreads();
        for (int off = 1; off < 256; off <<= 1) {
            int t = (tid >= off) ? tmp[tid - off] : 0;
            __syncthreads();
            tmp[tid] += t;
            __syncthreads();
        }
        if (i < NBLK) arr[i] = tmp[tid] - vL + carry;
        int tot = tmp[255];
        __syncthreads();
        carry += tot;
    }
    if (tid == 0) binCount[b] = carry;
}

// ---- Pass 3: exclusive scan of 64 bin totals (one wave) ----
__global__ void base_kernel(const int* __restrict__ binCount, int* __restrict__ binBase)
{
    int lane = threadIdx.x;   // 64 threads
    int v = binCount[lane];
    int incl = v;
    for (int off = 1; off < 64; off <<= 1) {
        int t = __shfl_up(incl, off, 64);
        if (lane >= off) incl += t;
    }
    binBase[lane] = incl - v;
}

// ---- Pass 4: stable scatter of particle indices ----
__global__ __launch_bounds__(256) void scatter_kernel(
    const float2* __restrict__ x, const int* __restrict__ blockHist,
    const int* __restrict__ binBase, int* __restrict__ sortedIdx)
{
    __shared__ int lcnt[NBINS];
    int tid = threadIdx.x, bid = blockIdx.x;
    if (tid < NBINS) lcnt[tid] = 0;
    __syncthreads();
    int n = bid * 256 + tid;
    if (n < NPART) {
        int tile = tile_of(x[n]);
        int r = atomicAdd(&lcnt[tile], 1);
        int pos = binBase[tile] + blockHist[tile * NBLK + bid] + r;
        sortedIdx[pos] = n;
    }
}

// ---- Pass 5: tiled P2G with LDS subgrid (affine folded into momentum) ----
__global__ __launch_bounds__(P2G_THREADS) void p2g_tiled_kernel(
    const float2* __restrict__ x, const float2* __restrict__ v,
    const float4* __restrict__ C, const float4* __restrict__ F,
    const int* __restrict__ material, const float* __restrict__ Jp,
    const int* __restrict__ sortedIdx, const int* __restrict__ binBase,
    const int* __restrict__ binCount,
    float* __restrict__ gv, float* __restrict__ gm)
{
    __shared__ float s_v0[SUBN], s_v1[SUBN], s_m[SUBN];
    int tid = threadIdx.x;
    int tile = blockIdx.x >> 3;       // / P2G_SUB
    int sub  = blockIdx.x & (P2G_SUB - 1);
    for (int i = tid; i < SUBN; i += P2G_THREADS) {
        s_v0[i] = 0.f; s_v1[i] = 0.f; s_m[i] = 0.f;
    }
    __syncthreads();
    int start = binBase[tile];
    int cnt = binCount[tile];
    int t0 = (tile >> 3) << 4;
    int t1 = (tile & 7) << 4;
    const float DX = 1.0f / 128.0f;
    const float P_MASS = 1.52587890625e-05f;

    for (int p = sub * P2G_THREADS + tid; p < cnt; p += P2G_SUB * P2G_THREADS) {
        int n = sortedIdx[start + p];
        float2 xx = x[n];
        float2 vv = v[n];
        float4 Cm = C[n];
        float4 Fin = F[n];
        int mat = material[n];
        float jp = Jp[n];
        PhysOut po = particle_phys(xx, vv, Cm, Fin, mat, jp);

        float xg0 = xx.x * 128.0f, xg1 = xx.y * 128.0f;
        int b0 = (int)floorf(xg0 - 0.5f), b1 = (int)floorf(xg1 - 0.5f);
        float fx0 = xg0 - (float)b0, fx1 = xg1 - (float)b1;
        float wx[3], wy[3];
        quad_weights(fx0, wx);
        quad_weights(fx1, wy);
        int l0 = b0 - t0, l1 = b1 - t1;
        #pragma unroll
        for (int i = 0; i < 3; ++i) {
            float nx0 = (float)(b0 + i) * DX;
            #pragma unroll
            for (int j = 0; j < 3; ++j) {
                float wt = wx[i] * wy[j];
                float nx1 = (float)(b1 + j) * DX;
                int l = (l0 + i) * SUBW + (l1 + j);
                atomicAdd(&s_v0[l], wt * (po.mom0 + po.aff00 * nx0 + po.aff01 * nx1));
                atomicAdd(&s_v1[l], wt * (po.mom1 + po.aff10 * nx0 + po.aff11 * nx1));
                atomicAdd(&s_m[l], wt * P_MASS);
            }
        }
    }
    __syncthreads();
    for (int l = tid; l < SUBN; l += P2G_THREADS) {
        float m = s_m[l];
        if (m != 0.f) {
            int gi = t0 + l / SUBW, gj = t1 + l % SUBW;
            if (gi < NGRID && gj < NGRID) {
                int g = gi * NGRID + gj;
                unsafeAtomicAdd(&gv[2 * g], s_v0[l]);
                unsafeAtomicAdd(&gv[2 * g + 1], s_v1[l]);
                unsafeAtomicAdd(&gm[g], m);
            }
        }
    }
}

// ---- Pass 6: grid update (aff already folded in) ----
__global__ __launch_bounds__(256) void grid_kernel(
    float* __restrict__ gv, const float* __restrict__ gm)
{
    int idx = blockIdx.x * blockDim.x + threadIdx.x;
    if (idx >= NNODES) return;
    int i = idx >> 7, j = idx & 127;
    float m = gm[idx];
    float v0 = gv[2 * idx], v1 = gv[2 * idx + 1];
    if (m > 0.0f) {
        v0 /= m;
        v1 /= m;
        v1 -= 5e-3f;   // -DT*50
    }
    if (i < 3) v0 = fmaxf(v0, 0.0f);
    if (i >= NGRID - 2) v0 = fminf(v0, 0.0f);
    if (j < 3) v1 = fmaxf(v1, 0.0f);
    if (j >= NGRID - 2) v1 = fminf(v1, 0.0f);
    gv[2 * idx] = v0;
    gv[2 * idx + 1] = v1;
}

// ---- Pass 7: G2P + recompute per-particle outputs (coalesced writes) ----
__global__ __launch_bounds__(256) void g2p_kernel(
    const float2* __restrict__ x, const float4* __restrict__ C,
    const float4* __restrict__ F, const int* __restrict__ material,
    const float* __restrict__ Jp, const float* __restrict__ gv,
    float* __restrict__ out)
{
    int n = blockIdx.x * blockDim.x + threadIdx.x;
    if (n >= NPART) return;
    const float DX = 1.0f / 128.0f;
    const float DT = 1e-4f;
    const float K4 = 65536.0f;

    float2 xx = x[n];
    float4 Cm = C[n];
    float4 Fin = F[n];
    int mat = material[n];
    float jp = Jp[n];

    PhysOut po = particle_phys(xx, make_float2(0.f, 0.f), Cm, Fin, mat, jp);
    ((float4*)(out + OUT_F))[n] = make_float4(po.o00, po.o01, po.o10, po.o11);
    out[OUT_MAT + n] = (float)mat;
    out[OUT_JP + n] = po.jp_new;

    float xg0 = xx.x * 128.0f, xg1 = xx.y * 128.0f;
    int b0 = (int)floorf(xg0 - 0.5f), b1 = (int)floorf(xg1 - 0.5f);
    float fx0 = xg0 - (float)b0, fx1 = xg1 - (float)b1;
    float wx[3], wy[3];
    quad_weights(fx0, wx);
    quad_weights(fx1, wy);

    float nv0 = 0.f, nv1 = 0.f;
    float nC00 = 0.f, nC01 = 0.f, nC10 = 0.f, nC11 = 0.f;
    #pragma unroll
    for (int i = 0; i < 3; ++i) {
        float node0 = (float)(b0 + i) * DX;
        #pragma unroll
        for (int j = 0; j < 3; ++j) {
            float wt = wx[i] * wy[j];
            int idx = (b0 + i) * NGRID + (b1 + j);
            float g0 = gv[2 * idx], g1 = gv[2 * idx + 1];
            float node1 = (float)(b1 + j) * DX;
            nv0 += wt * g0;
            nv1 += wt * g1;
            nC00 += wt * g0 * node0;
            nC01 += wt * g0 * node1;
            nC10 += wt * g1 * node0;
            nC11 += wt * g1 * node1;
        }
    }
    nC00 = (nC00 - nv0 * xx.x) * K4;
    nC01 = (nC01 - nv0 * xx.y) * K4;
    nC10 = (nC10 - nv1 * xx.x) * K4;
    nC11 = (nC11 - nv1 * xx.y) * K4;

    ((float2*)(out + OUT_X))[n] = make_float2(xx.x + DT * nv0, xx.y + DT * nv1);
    ((float2*)(out + OUT_V))[n] = make_float2(nv0, nv1);
    ((float4*)(out + OUT_C))[n] = make_float4(nC00, nC01, nC10, nC11);
}

extern "C" void kernel_launch(void* const* d_in, const int* in_sizes, int n_in,
                              void* d_out, int out_size, void* d_ws, size_t ws_size,
                              hipStream_t stream)
{
    const float2* x = (const float2*)d_in[0];
    const float2* v = (const float2*)d_in[1];
    const float4* C = (const float4*)d_in[2];
    const float4* F = (const float4*)d_in[3];
    const int* material = (const int*)d_in[4];
    const float* Jp = (const float*)d_in[5];
    float* out = (float*)d_out;

    // workspace layout (~5.2 MB)
    float* gv = (float*)d_ws;                       // 2*NNODES floats
    float* gm = gv + 2 * NNODES;                    // NNODES floats
    int* binBase = (int*)(gm + NNODES);             // 64
    int* binCount = binBase + NBINS;                // 64
    int* blockHist = binCount + NBINS;              // NBINS*NBLK
    int* sortedIdx = blockHist + NBINS * NBLK;      // NPART

    hipMemsetAsync(d_ws, 0, (size_t)(3 * NNODES) * sizeof(float), stream);

    hist_kernel<<<NBLK, 256, 0, stream>>>(x, blockHist);
    scan_kernel<<<NBINS, 256, 0, stream>>>(blockHist, binCount);
    base_kernel<<<1, 64, 0, stream>>>(binCount, binBase);
    scatter_kernel<<<NBLK, 256, 0, stream>>>(x, blockHist, binBase, sortedIdx);
    p2g_tiled_kernel<<<NBINS * P2G_SUB, P2G_THREADS, 0, stream>>>(
        x, v, C, F, material, Jp, sortedIdx, binBase, binCount, gv, gm);
    grid_kernel<<<NNODES / 256, 256, 0, stream>>>(gv, gm);
    g2p_kernel<<<(NPART + 255) / 256, 256, 0, stream>>>(x, C, F, material, Jp, gv, out);
}